// Round 15
// baseline (138.655 us; speedup 1.0000x reference)
//
#include <hip/hip_runtime.h>

// CostVolume2D: B=8, H=256, W=512, C=32, n_disp=12, stride=1.
// cost[b,h,w,d] = sum_c |feat_l[b,h,w,c] - feat_r[b,h,w-d,c]|, feat_r zero-padded left.
//
// r15 = r11 shell + conflict-free P=2 reads + r11's-failure fix (VGPR).
// Block = 256 threads = one full row; thread t owns pixels (2t, 2t+1).
//
// LDS: 8 planes x 512 slots = 64KB, single stage, no halo (negative cols are
// the zero-pad case; junk reads for t<6 overwritten by lsum fixup — verified r11).
// Parity-permuted layout: within each 64-col window k, even cols -> slots
// k*64+0..31, odd cols -> k*64+32..63  (slot(n,p) = 64*(n>>5) + (n&31) + 32p,
// n = col>>1, p = col&1). Applied on the glld SOURCE lane order only: each
// instr's address SET is still 64 consecutive cols x 16B — the exact sectors
// of r7/r11's compulsory-FETCH staging (131MB). Dest stays lane-linear (legal).
// Reads at fixed (q,E): col = 2t+E-11 -> n = t+m (m in [-6,0]), so every
// 16-lane quarter-wave covers a CONTIGUOUS slot run = the measured 0-conflict
// condition (r4/r5/r7), vs r10's stride-2 4-way conflicts.
// 13 cols serve 24 (pixel,d) pairs -> 52 ds_read_b128/pixel (r7: 96).
// VGPR control (r11 died at 216): #pragma unroll 1 over q + 1-iter look-ahead
// of the two feat_l float4s with statically named regs.

constexpr int ND = 12;

typedef float vfloat4 __attribute__((ext_vector_type(4)));

__device__ __forceinline__ float l1_4(float4 a, float4 b) {
    return fabsf(a.x - b.x) + fabsf(a.y - b.y) + fabsf(a.z - b.z) + fabsf(a.w - b.w);
}
__device__ __forceinline__ float abs4(float4 a) {
    return fabsf(a.x) + fabsf(a.y) + fabsf(a.z) + fabsf(a.w);
}

__global__ __launch_bounds__(256) void cost_volume_kernel(
    const float* __restrict__ fl,
    const float* __restrict__ fr,
    float* __restrict__ out)
{
    __shared__ float4 lds4[8 * 512];               // 65536 B

    const int t    = threadIdx.x;                  // pixel pair (2t, 2t+1)
    const int wave = t >> 6;
    const int lane = t & 63;
    const int bh   = blockIdx.x;                   // b*H + h
    const float* fr_row = fr + (size_t)bh * 512 * 32;

    // ---- stage all 8 planes: 64 runs, wave w takes r = w + 4j.
    // dest slot = ql*512 + k*64 + lane (linear); source col parity-permuted.
    #pragma unroll
    for (int j = 0; j < 16; ++j) {
        const int r  = wave + 4 * j;
        const int ql = r >> 3;
        const int k  = r & 7;
        const int col = (k << 6) + 2 * (lane & 31) + (lane >> 5);
        __builtin_amdgcn_global_load_lds(
            (const __attribute__((address_space(1))) void*)(fr_row + (size_t)col * 32 + ql * 4),
            (__attribute__((address_space(3))) void*)(lds4 + (ql << 9) + (k << 6) + lane),
            16, 0, 0);
    }

    const size_t pix0 = (size_t)bh * 512 + 2 * t;
    const float4* lp0 = reinterpret_cast<const float4*>(fl) + pix0 * 8;
    const float4* lp1 = lp0 + 8;

    // 7 read-base byte offsets: n = t+m, m = mm-6; slot_base = 64*(n>>5)+(n&31).
    int baseb[7];
    #pragma unroll
    for (int mm = 0; mm < 7; ++mm) {
        const int n = t + mm - 6;
        baseb[mm] = (((n >> 5) << 6) + (n & 31)) << 4;   // byte offset (can be <0: t<6 junk, fixed up)
    }

    float res0[ND], res1[ND];
    #pragma unroll
    for (int d = 0; d < ND; ++d) { res0[d] = 0.f; res1[d] = 0.f; }
    float lsum0 = 0.f, lsum1 = 0.f;

    __syncthreads();                               // drains glld + visibility

    const char* pl = (const char*)lds4;
    float4 a0 = lp0[0], a1 = lp1[0];
    #pragma unroll 1
    for (int q = 0; q < 8; ++q) {
        // look-ahead feat_l for next iter (statically named; wraps to 0 at q=7, L1-hot)
        const int qn = (q + 1) & 7;
        float4 nx0 = lp0[qn], nx1 = lp1[qn];

        lsum0 += abs4(a0);
        lsum1 += abs4(a1);

        const int qb = q << 13;                    // q*8192 bytes per plane
        #pragma unroll
        for (int E = 0; E <= 12; ++E) {            // col = 2t + E - 11
            const int p    = 1 - (E & 1);          // even E -> odd col -> p=1
            const int midx = (E + (E & 1)) >> 1;   // n-group index
            const float4 rv = *reinterpret_cast<const float4*>(
                pl + baseb[midx] + (qb + (p << 9)));
            if (E <= 11) res0[11 - E] += l1_4(a0, rv);   // d0 = 11-E
            if (E >= 1)  res1[12 - E] += l1_4(a1, rv);   // d1 = 12-E
        }
        a0 = nx0; a1 = nx1;
    }

    // ---- left edge: w < d -> feat_r fully shifted out (zeros) -> sum|feat_l|
    if (t < 6) {
        #pragma unroll
        for (int d = 0; d < ND; ++d) {
            if (d > 2 * t)     res0[d] = lsum0;
            if (d > 2 * t + 1) res1[d] = lsum1;
        }
    }

    // ---- nontemporal stores: 24 contiguous floats/thread
    vfloat4* op = reinterpret_cast<vfloat4*>(out + pix0 * ND);
    vfloat4 o0 = {res0[0], res0[1], res0[2],  res0[3]};
    vfloat4 o1 = {res0[4], res0[5], res0[6],  res0[7]};
    vfloat4 o2 = {res0[8], res0[9], res0[10], res0[11]};
    vfloat4 o3 = {res1[0], res1[1], res1[2],  res1[3]};
    vfloat4 o4 = {res1[4], res1[5], res1[6],  res1[7]};
    vfloat4 o5 = {res1[8], res1[9], res1[10], res1[11]};
    __builtin_nontemporal_store(o0, op + 0);
    __builtin_nontemporal_store(o1, op + 1);
    __builtin_nontemporal_store(o2, op + 2);
    __builtin_nontemporal_store(o3, op + 3);
    __builtin_nontemporal_store(o4, op + 4);
    __builtin_nontemporal_store(o5, op + 5);
}

extern "C" void kernel_launch(void* const* d_in, const int* in_sizes, int n_in,
                              void* d_out, int out_size, void* d_ws, size_t ws_size,
                              hipStream_t stream)
{
    const float* fl = (const float*)d_in[0];
    const float* fr = (const float*)d_in[1];
    float* out = (float*)d_out;

    const int grid = 8 * 256;                      // one block per (b, h) row
    cost_volume_kernel<<<grid, 256, 0, stream>>>(fl, fr, out);
}